// Round 9
// baseline (349.974 us; speedup 1.0000x reference)
//
#include <hip/hip_runtime.h>
#include <hip/hip_bf16.h>
#include <math.h>

#define T_TOK 4096
#define D_EMB 768
#define DFF   3072
#define N_EXP 8
#define MAXT  72   // max row-tiles: 8192/128 + 8 partials
#define CNTS  16   // cnt padding stride (ints) -> one 64B line per expert

typedef __attribute__((ext_vector_type(8))) short bf16x8;
typedef __attribute__((ext_vector_type(4))) float f32x4;

__device__ __forceinline__ short f2bf(float f) {
  union { __hip_bfloat16 b; short s; } u;
  u.b = __float2bfloat16(f);
  return u.s;
}

// tanh-form GELU (max |err| vs exact erf-GELU ~3e-4 — far below threshold)
__device__ __forceinline__ float gelu_f(float v) {
  float u = 0.7978845608f * v * (1.0f + 0.044715f * v * v);
  float a = fabsf(u);
  float em = __expf(-2.0f * a);
  float th = (1.0f - em) / (1.0f + em);
  th = (u < 0.0f) ? -th : th;
  return 0.5f * v * (1.0f + th);
}

// ---------------- zero out + counters ----------------
__global__ void zero_init_kernel(float4* __restrict__ out4, int n4, int* __restrict__ cnt) {
  int i = blockIdx.x * blockDim.x + threadIdx.x;
  if (i < N_EXP * CNTS) cnt[i] = 0;
  float4 z; z.x = z.y = z.z = z.w = 0.f;
  for (int j = i; j < n4; j += gridDim.x * blockDim.x) out4[j] = z;
}

// ---------------- x fp32 -> bf16 ----------------
__global__ void cast_x_kernel(const float4* __restrict__ in, short4* __restrict__ outp, int n4) {
  int i = blockIdx.x * blockDim.x + threadIdx.x;
  if (i >= n4) return;
  float4 v = in[i];
  short4 o;
  o.x = f2bf(v.x); o.y = f2bf(v.y); o.z = f2bf(v.z); o.w = f2bf(v.w);
  outp[i] = o;
}

// ---------------- weight transpose+cast: [e][R][C] f32 -> [e][C][R] bf16 ----------------
__global__ void transpose_cast_kernel(const float* __restrict__ in, short* __restrict__ outp,
                                      int R, int C) {
  __shared__ float tile[64][65];
  int e = blockIdx.z;
  int c0 = blockIdx.x * 64, r0 = blockIdx.y * 64;
  const float* src = in + (size_t)e * R * C;
  short* dst = outp + (size_t)e * R * C;
  int tid = threadIdx.x;
#pragma unroll
  for (int it = 0; it < 4; ++it) {
    int idx = tid + it * 256;
    int r = idx >> 4;
    int c4 = idx & 15;
    float4 v = *(const float4*)&src[(size_t)(r0 + r) * C + c0 + c4 * 4];
    tile[r][c4 * 4 + 0] = v.x; tile[r][c4 * 4 + 1] = v.y;
    tile[r][c4 * 4 + 2] = v.z; tile[r][c4 * 4 + 3] = v.w;
  }
  __syncthreads();
#pragma unroll
  for (int it = 0; it < 4; ++it) {
    int idx = tid + it * 256;
    int c = idx >> 4;
    int rr = idx & 15;
    short4 o;
    o.x = f2bf(tile[rr * 4 + 0][c]);
    o.y = f2bf(tile[rr * 4 + 1][c]);
    o.z = f2bf(tile[rr * 4 + 2][c]);
    o.w = f2bf(tile[rr * 4 + 3][c]);
    *(short4*)&dst[(size_t)(c0 + c) * R + r0 + rr * 4] = o;
  }
}

// ---------------- gate: 16 tokens/block, LDS-aggregated routing ----------------
__global__ __launch_bounds__(256)
void gate_kernel(const float* __restrict__ x, const float* __restrict__ gw,
                 int* __restrict__ cnt, int* __restrict__ tok,
                 float* __restrict__ wgt) {
  __shared__ int lcnt[N_EXP];
  __shared__ int gbase[N_EXP];
  __shared__ int le[32];
  __shared__ float lw[32];
  __shared__ int lpos[32];
  int tid = threadIdx.x, lane = tid & 63, wid = tid >> 6;
  if (tid < N_EXP) lcnt[tid] = 0;
  __syncthreads();

#pragma unroll
  for (int i = 0; i < 4; i++) {
    int t = blockIdx.x * 16 + wid * 4 + i;
    float s[N_EXP];
#pragma unroll
    for (int e = 0; e < N_EXP; e++) s[e] = 0.f;
#pragma unroll
    for (int dd = 0; dd < D_EMB / 64; dd++) {
      int d = dd * 64 + lane;
      float xv = x[(size_t)t * D_EMB + d];
#pragma unroll
      for (int e = 0; e < N_EXP; e++) s[e] += xv * gw[d * N_EXP + e];
    }
#pragma unroll
    for (int e = 0; e < N_EXP; e++) {
#pragma unroll
      for (int off = 32; off > 0; off >>= 1) s[e] += __shfl_xor(s[e], off, 64);
    }
    if (lane == 0) {
      int e0 = 0;
#pragma unroll
      for (int e = 1; e < N_EXP; e++) if (s[e] > s[e0]) e0 = e;
      int e1 = -1;
#pragma unroll
      for (int e = 0; e < N_EXP; e++) {
        if (e == e0) continue;
        if (e1 < 0 || s[e] > s[e1]) e1 = e;
      }
      float p1 = __expf(s[e1] - s[e0]);
      float inv = 1.f / (1.f + p1);
      int idx = (wid * 4 + i) * 2;
      le[idx] = e0; lw[idx] = inv;           lpos[idx] = atomicAdd(&lcnt[e0], 1);
      le[idx + 1] = e1; lw[idx + 1] = p1 * inv; lpos[idx + 1] = atomicAdd(&lcnt[e1], 1);
    }
  }
  __syncthreads();
  if (tid < N_EXP) gbase[tid] = atomicAdd(&cnt[tid * CNTS], lcnt[tid]);
  __syncthreads();
  if (tid < 32) {
    int e = le[tid];
    int t = blockIdx.x * 16 + (tid >> 1);
    int p = gbase[e] + lpos[tid];
    tok[e * T_TOK + p] = t;
    wgt[e * T_TOK + p] = lw[tid];
  }
}

// ---------------- plan: offsets + compacted (expert, row-tile) list ----------------
__global__ void plan_kernel(const int* __restrict__ cnt, int* __restrict__ offs,
                            int* __restrict__ tile_e, int* __restrict__ tile_rt,
                            int* __restrict__ ntiles) {
  if (threadIdx.x != 0 || blockIdx.x != 0) return;
  int o = 0, nt = 0;
  for (int e = 0; e < N_EXP; e++) {
    offs[e] = o;
    int tc = (cnt[e * CNTS] + 127) >> 7;
    for (int i = 0; i < tc; i++) { tile_e[nt] = e; tile_rt[nt] = i; nt++; }
    o += cnt[e * CNTS];
  }
  *ntiles = nt;
}

// ---------------- grouped GEMM: 128x128 tile, BK=32, REG-STAGED 3-buffer pipeline.
// Per step t: issue global_load_dwordx4 for tile t+2 -> reg-set t%2;
//             ds_write tile t+1 from reg-set (t+1)%2 (compiler emits COUNTED vmcnt
//             waits on just those regs - the new loads stay in flight);
//             raw s_barrier (no vmcnt(0) drain - this is the whole point);
//             ds_read frags + 16 MFMA on buffer t%3.
// MFMA operands SWAPPED: mfma(bv, af) -> acc[m][n][j] holds row=wr+m*16+(lane&15),
// col=wc+n*16+(lane>>4)*4+j  => 4 consecutive cols per reg => 8B packed stores.
template<int KDIM, int NDIM, int SPLITK, int EPI>
__global__ __launch_bounds__(256, 3)
void moe_gemm(const short* __restrict__ A, const short* __restrict__ Bw,
              const int* __restrict__ tok, const float* __restrict__ wgt,
              const int* __restrict__ cnt, const int* __restrict__ offs,
              const int* __restrict__ tile_e, const int* __restrict__ tile_rt,
              const int* __restrict__ ntiles,
              short* __restrict__ hout, float* __restrict__ fout) {
  const int COLT = NDIM / 128;
  const int KS = KDIM / SPLITK;
  const int NKT = KS / 32;              // 24 (FC), 48 (PROJ)
  static_assert(NKT % 6 == 0 && NKT >= 12, "pipeline needs NKT%6==0");

  int nwg = gridDim.x;
  int cpx = nwg >> 3;
  int logical = (blockIdx.x & 7) * cpx + (blockIdx.x >> 3);   // bijective XCD swizzle
  int ct = logical % COLT;
  int tile = (logical / COLT) % MAXT;
  int sk = logical / (COLT * MAXT);
  if (tile >= *ntiles) return;
  int e = tile_e[tile], rt = tile_rt[tile];
  int ne = cnt[e * CNTS];
  int base = offs[e];

  __shared__ __align__(16) short A0[4096], B0[4096], A1[4096], B1[4096], A2[4096], B2[4096];

  int tid = threadIdx.x;
  int lane = tid & 63;
  int wid = tid >> 6;

  // staging map: seg in [0,512), row = seg>>2, physical slot p = seg&3 holds
  // logical 16B k-chunk q = p ^ ((row ^ (row>>2)) & 3); read side same XOR.
  const short* aptr0; const short* aptr1;
  const short* bptr0; const short* bptr1;
  int lofs0, lofs1;
  {
    int seg = tid;
    int row = seg >> 2, p = seg & 3;
    int q = p ^ ((row ^ (row >> 2)) & 3);
    int r = rt * 128 + row; if (r >= ne) r = ne - 1;
    size_t ga = (EPI == 0) ? (size_t)tok[e * T_TOK + r] : (size_t)(base + r);
    aptr0 = A + ga * KDIM + sk * KS + q * 8;
    bptr0 = Bw + ((size_t)e * NDIM + ct * 128 + row) * KDIM + sk * KS + q * 8;
    lofs0 = seg * 8;
  }
  {
    int seg = tid + 256;
    int row = seg >> 2, p = seg & 3;
    int q = p ^ ((row ^ (row >> 2)) & 3);
    int r = rt * 128 + row; if (r >= ne) r = ne - 1;
    size_t ga = (EPI == 0) ? (size_t)tok[e * T_TOK + r] : (size_t)(base + r);
    aptr1 = A + ga * KDIM + sk * KS + q * 8;
    bptr1 = Bw + ((size_t)e * NDIM + ct * 128 + row) * KDIM + sk * KS + q * 8;
    lofs1 = seg * 8;
  }

  int wr = (wid >> 1) * 64, wc = (wid & 1) * 64;
  int cb = lane >> 4;

  int offa[4], offb[4];
#pragma unroll
  for (int m = 0; m < 4; m++) {
    int row = wr + m * 16 + (lane & 15);
    offa[m] = row * 32 + (cb ^ ((row ^ (row >> 2)) & 3)) * 8;
  }
#pragma unroll
  for (int n = 0; n < 4; n++) {
    int row = wc + n * 16 + (lane & 15);
    offb[n] = row * 32 + (cb ^ ((row ^ (row >> 2)) & 3)) * 8;
  }

  f32x4 acc[4][4];
#pragma unroll
  for (int m = 0; m < 4; m++)
#pragma unroll
    for (int n = 0; n < 4; n++) acc[m][n] = (f32x4){0.f, 0.f, 0.f, 0.f};

  // two pending-load register sets (tile u -> set u%2)
  f32x4 s0a0, s0a1, s0b0, s0b1;
  f32x4 s1a0, s1a1, s1b0, s1b1;

#define LOADS0(K0) do { s0a0 = *(const f32x4*)(aptr0 + (K0)); s0a1 = *(const f32x4*)(aptr1 + (K0)); \
                        s0b0 = *(const f32x4*)(bptr0 + (K0)); s0b1 = *(const f32x4*)(bptr1 + (K0)); } while (0)
#define LOADS1(K0) do { s1a0 = *(const f32x4*)(aptr0 + (K0)); s1a1 = *(const f32x4*)(aptr1 + (K0)); \
                        s1b0 = *(const f32x4*)(bptr0 + (K0)); s1b1 = *(const f32x4*)(bptr1 + (K0)); } while (0)
#define WR0(AW, BW) do { *(f32x4*)((AW) + lofs0) = s0a0; *(f32x4*)((AW) + lofs1) = s0a1; \
                         *(f32x4*)((BW) + lofs0) = s0b0; *(f32x4*)((BW) + lofs1) = s0b1; } while (0)
#define WR1(AW, BW) do { *(f32x4*)((AW) + lofs0) = s1a0; *(f32x4*)((AW) + lofs1) = s1a1; \
                         *(f32x4*)((BW) + lofs0) = s1b0; *(f32x4*)((BW) + lofs1) = s1b1; } while (0)
#define BAR() do { __builtin_amdgcn_sched_barrier(0); __builtin_amdgcn_s_barrier(); \
                   __builtin_amdgcn_sched_barrier(0); } while (0)
#define COMPUTE(AR, BR) do {                                                   \
    bf16x8 af_[4], bv_[4];                                                     \
    _Pragma("unroll") for (int m_ = 0; m_ < 4; ++m_)                           \
      af_[m_] = *(const bf16x8*)((AR) + offa[m_]);                             \
    _Pragma("unroll") for (int n_ = 0; n_ < 4; ++n_)                           \
      bv_[n_] = *(const bf16x8*)((BR) + offb[n_]);                             \
    _Pragma("unroll") for (int m_ = 0; m_ < 4; ++m_)                           \
      _Pragma("unroll") for (int n_ = 0; n_ < 4; ++n_)                         \
        acc[m_][n_] = __builtin_amdgcn_mfma_f32_16x16x32_bf16(                 \
            bv_[n_], af_[m_], acc[m_][n_], 0, 0, 0);                           \
  } while (0)

  // prologue: tile0 -> set0, tile1 -> set1, write tile0 to buf0
  LOADS0(0);
  LOADS1(32);
  WR0(A0, B0);

  // full groups of 6 steps: t = 6g .. 6g+5, all with loads (t+2 <= NKT-1) and writes
  int kb = 64;   // k-offset (shorts) of tile t+2 at t=0
  for (int g = 0; g < (NKT - 6) / 6; ++g) {
    LOADS0(kb +   0); WR1(A1, B1); BAR(); COMPUTE(A0, B0);   // t=6g
    LOADS1(kb +  32); WR0(A2, B2); BAR(); COMPUTE(A1, B1);   // t=6g+1
    LOADS0(kb +  64); WR1(A0, B0); BAR(); COMPUTE(A2, B2);   // t=6g+2
    LOADS1(kb +  96); WR0(A1, B1); BAR(); COMPUTE(A0, B0);   // t=6g+3
    LOADS0(kb + 128); WR1(A2, B2); BAR(); COMPUTE(A1, B1);   // t=6g+4
    LOADS1(kb + 160); WR0(A0, B0); BAR(); COMPUTE(A2, B2);   // t=6g+5
    kb += 192;
  }
  // tail: t = NKT-6 .. NKT-1
  LOADS0(kb +   0); WR1(A1, B1); BAR(); COMPUTE(A0, B0);     // t=NKT-6
  LOADS1(kb +  32); WR0(A2, B2); BAR(); COMPUTE(A1, B1);     // t=NKT-5
  LOADS0(kb +  64); WR1(A0, B0); BAR(); COMPUTE(A2, B2);     // t=NKT-4
  LOADS1(kb +  96); WR0(A1, B1); BAR(); COMPUTE(A0, B0);     // t=NKT-3
  WR1(A2, B2);      BAR(); COMPUTE(A1, B1);                  // t=NKT-2 (no loads)
  BAR(); COMPUTE(A2, B2);                                    // t=NKT-1 (drain)

#undef LOADS0
#undef LOADS1
#undef WR0
#undef WR1
#undef BAR
#undef COMPUTE

  // epilogue — swapped layout: row = wr+m*16+(lane&15), cols = wc+n*16+(lane>>4)*4+j
  int colq = ct * 128 + wc + ((lane >> 4) << 2);
#pragma unroll
  for (int m = 0; m < 4; m++) {
    int rloc = rt * 128 + wr + m * 16 + (lane & 15);
    if (rloc < ne) {
      if (EPI == 0) {
        size_t hrow = (size_t)(base + rloc) * NDIM;
#pragma unroll
        for (int n = 0; n < 4; n++) {
          unsigned int lo = (unsigned short)f2bf(gelu_f(acc[m][n][0])) |
                            ((unsigned int)(unsigned short)f2bf(gelu_f(acc[m][n][1])) << 16);
          unsigned int hi = (unsigned short)f2bf(gelu_f(acc[m][n][2])) |
                            ((unsigned int)(unsigned short)f2bf(gelu_f(acc[m][n][3])) << 16);
          uint2 v; v.x = lo; v.y = hi;
          *(uint2*)&hout[hrow + colq + n * 16] = v;
        }
      } else {
        int t = tok[e * T_TOK + rloc];
        float w = wgt[e * T_TOK + rloc];
        float* orow = fout + (size_t)t * NDIM + colq;
#pragma unroll
        for (int n = 0; n < 4; n++)
#pragma unroll
          for (int j = 0; j < 4; j++)
            atomicAdd(orow + n * 16 + j, w * acc[m][n][j]);
      }
    }
  }
}

extern "C" void kernel_launch(void* const* d_in, const int* in_sizes, int n_in,
                              void* d_out, int out_size, void* d_ws, size_t ws_size,
                              hipStream_t stream) {
  const float* x   = (const float*)d_in[0];
  const float* gw  = (const float*)d_in[1];
  const float* wfc = (const float*)d_in[2];
  const float* wpj = (const float*)d_in[3];
  float* out = (float*)d_out;

  char* ws = (char*)d_ws;
  const size_t SZ_XB = (size_t)T_TOK * D_EMB * 2;
  const size_t SZ_W  = (size_t)N_EXP * D_EMB * DFF * 2;
  const size_t SZ_H  = (size_t)2 * T_TOK * DFF * 2;
  short* xb   = (short*)(ws);
  short* wfcT = (short*)(ws + SZ_XB);
  short* wpjT = (short*)(ws + SZ_XB + SZ_W);
  short* h    = (short*)(ws + SZ_XB + 2 * SZ_W);
  char* p2    = ws + SZ_XB + 2 * SZ_W + SZ_H;
  int*   tok  = (int*)(p2);
  float* wgt  = (float*)(p2 + (size_t)N_EXP * T_TOK * 4);
  char* p3    = p2 + (size_t)N_EXP * T_TOK * 8;
  int*   cnt     = (int*)(p3);                     // padded: N_EXP*CNTS ints
  int*   offs    = (int*)(p3 + 1024);
  int*   tile_e  = (int*)(p3 + 1024 + 64);
  int*   tile_rt = (int*)(p3 + 1024 + 64 + 512);
  int*   ntiles  = (int*)(p3 + 1024 + 64 + 1024);

  int n4 = out_size / 4;
  zero_init_kernel<<<2048, 256, 0, stream>>>((float4*)out, n4, cnt);
  cast_x_kernel<<<(T_TOK * D_EMB / 4 + 255) / 256, 256, 0, stream>>>(
      (const float4*)x, (short4*)xb, T_TOK * D_EMB / 4);
  transpose_cast_kernel<<<dim3(DFF / 64, D_EMB / 64, N_EXP), 256, 0, stream>>>(wfc, wfcT, D_EMB, DFF);
  transpose_cast_kernel<<<dim3(D_EMB / 64, DFF / 64, N_EXP), 256, 0, stream>>>(wpj, wpjT, DFF, D_EMB);
  gate_kernel<<<T_TOK / 16, 256, 0, stream>>>(x, gw, cnt, tok, wgt);
  plan_kernel<<<1, 1, 0, stream>>>(cnt, offs, tile_e, tile_rt, ntiles);
  // FC: K=768 (NKT=24), N=3072. grid = 72*24 = 1728 (%8==0)
  moe_gemm<D_EMB, DFF, 1, 0><<<MAXT * (DFF / 128), 256, 0, stream>>>(
      xb, wfcT, tok, wgt, cnt, offs, tile_e, tile_rt, ntiles, h, nullptr);
  // PROJ: K=3072 split 2 ways (NKT=48), N=768. grid = 2*72*6 = 864 (%8==0)
  moe_gemm<DFF, D_EMB, 2, 1><<<2 * MAXT * (D_EMB / 128), 256, 0, stream>>>(
      h, wpjT, tok, wgt, cnt, offs, tile_e, tile_rt, ntiles, nullptr, out);
}

// Round 10
// 244.726 us; speedup vs baseline: 1.4301x; 1.4301x over previous
//
#include <hip/hip_runtime.h>
#include <hip/hip_bf16.h>
#include <math.h>

#define T_TOK 4096
#define D_EMB 768
#define DFF   3072
#define N_EXP 8
#define MAXT2 40   // max 256-row tiles: 8192/256 + 8 partials
#define CNTS  16   // cnt padding stride (ints) -> one 64B line per expert

typedef __attribute__((ext_vector_type(8))) short bf16x8;
typedef __attribute__((ext_vector_type(4))) float f32x4;

typedef __attribute__((address_space(3))) unsigned int lds_u32_t;
typedef __attribute__((address_space(1))) unsigned int glob_u32_t;

__device__ __forceinline__ void gload16(const void* g, void* l) {
  __builtin_amdgcn_global_load_lds((const glob_u32_t*)g, (lds_u32_t*)l, 16, 0, 0);
}

__device__ __forceinline__ short f2bf(float f) {
  union { __hip_bfloat16 b; short s; } u;
  u.b = __float2bfloat16(f);
  return u.s;
}

// ---------------- zero out + counters ----------------
__global__ void zero_init_kernel(float4* __restrict__ out4, int n4, int* __restrict__ cnt) {
  int i = blockIdx.x * blockDim.x + threadIdx.x;
  if (i < N_EXP * CNTS) cnt[i] = 0;
  float4 z; z.x = z.y = z.z = z.w = 0.f;
  for (int j = i; j < n4; j += gridDim.x * blockDim.x) out4[j] = z;
}

// ---------------- x fp32 -> bf16 ----------------
__global__ void cast_x_kernel(const float4* __restrict__ in, short4* __restrict__ outp, int n4) {
  int i = blockIdx.x * blockDim.x + threadIdx.x;
  if (i >= n4) return;
  float4 v = in[i];
  short4 o;
  o.x = f2bf(v.x); o.y = f2bf(v.y); o.z = f2bf(v.z); o.w = f2bf(v.w);
  outp[i] = o;
}

// ---------------- weight transpose+cast: [e][R][C] f32 -> [e][C][R] bf16 ----------------
__global__ void transpose_cast_kernel(const float* __restrict__ in, short* __restrict__ outp,
                                      int R, int C) {
  __shared__ float tile[64][65];
  int e = blockIdx.z;
  int c0 = blockIdx.x * 64, r0 = blockIdx.y * 64;
  const float* src = in + (size_t)e * R * C;
  short* dst = outp + (size_t)e * R * C;
  int tid = threadIdx.x;
#pragma unroll
  for (int it = 0; it < 4; ++it) {
    int idx = tid + it * 256;
    int r = idx >> 4;
    int c4 = idx & 15;
    float4 v = *(const float4*)&src[(size_t)(r0 + r) * C + c0 + c4 * 4];
    tile[r][c4 * 4 + 0] = v.x; tile[r][c4 * 4 + 1] = v.y;
    tile[r][c4 * 4 + 2] = v.z; tile[r][c4 * 4 + 3] = v.w;
  }
  __syncthreads();
#pragma unroll
  for (int it = 0; it < 4; ++it) {
    int idx = tid + it * 256;
    int c = idx >> 4;
    int rr = idx & 15;
    short4 o;
    o.x = f2bf(tile[rr * 4 + 0][c]);
    o.y = f2bf(tile[rr * 4 + 1][c]);
    o.z = f2bf(tile[rr * 4 + 2][c]);
    o.w = f2bf(tile[rr * 4 + 3][c]);
    *(short4*)&dst[(size_t)(c0 + c) * R + r0 + rr * 4] = o;
  }
}

// ---------------- gate: 16 tokens/block, LDS-aggregated routing ----------------
__global__ __launch_bounds__(256)
void gate_kernel(const float* __restrict__ x, const float* __restrict__ gw,
                 int* __restrict__ cnt, int* __restrict__ tok,
                 float* __restrict__ wgt) {
  __shared__ int lcnt[N_EXP];
  __shared__ int gbase[N_EXP];
  __shared__ int le[32];
  __shared__ float lw[32];
  __shared__ int lpos[32];
  int tid = threadIdx.x, lane = tid & 63, wid = tid >> 6;
  if (tid < N_EXP) lcnt[tid] = 0;
  __syncthreads();

#pragma unroll
  for (int i = 0; i < 4; i++) {
    int t = blockIdx.x * 16 + wid * 4 + i;
    float s[N_EXP];
#pragma unroll
    for (int e = 0; e < N_EXP; e++) s[e] = 0.f;
#pragma unroll
    for (int dd = 0; dd < D_EMB / 64; dd++) {
      int d = dd * 64 + lane;
      float xv = x[(size_t)t * D_EMB + d];
#pragma unroll
      for (int e = 0; e < N_EXP; e++) s[e] += xv * gw[d * N_EXP + e];
    }
#pragma unroll
    for (int e = 0; e < N_EXP; e++) {
#pragma unroll
      for (int off = 32; off > 0; off >>= 1) s[e] += __shfl_xor(s[e], off, 64);
    }
    if (lane == 0) {
      int e0 = 0;
#pragma unroll
      for (int e = 1; e < N_EXP; e++) if (s[e] > s[e0]) e0 = e;
      int e1 = -1;
#pragma unroll
      for (int e = 0; e < N_EXP; e++) {
        if (e == e0) continue;
        if (e1 < 0 || s[e] > s[e1]) e1 = e;
      }
      float p1 = __expf(s[e1] - s[e0]);
      float inv = 1.f / (1.f + p1);
      int idx = (wid * 4 + i) * 2;
      le[idx] = e0; lw[idx] = inv;           lpos[idx] = atomicAdd(&lcnt[e0], 1);
      le[idx + 1] = e1; lw[idx + 1] = p1 * inv; lpos[idx + 1] = atomicAdd(&lcnt[e1], 1);
    }
  }
  __syncthreads();
  if (tid < N_EXP) gbase[tid] = atomicAdd(&cnt[tid * CNTS], lcnt[tid]);
  __syncthreads();
  if (tid < 32) {
    int e = le[tid];
    int t = blockIdx.x * 16 + (tid >> 1);
    int p = gbase[e] + lpos[tid];
    tok[e * T_TOK + p] = t;
    wgt[e * T_TOK + p] = lw[tid];
  }
}

// ---------------- plan: offsets + compacted (expert, 256-row-tile) list ----------------
__global__ void plan_kernel(const int* __restrict__ cnt, int* __restrict__ offs,
                            int* __restrict__ tile_e, int* __restrict__ tile_rt,
                            int* __restrict__ ntiles) {
  if (threadIdx.x != 0 || blockIdx.x != 0) return;
  int o = 0, nt = 0;
  for (int e = 0; e < N_EXP; e++) {
    offs[e] = o;
    int tc = (cnt[e * CNTS] + 255) >> 8;
    for (int i = 0; i < tc; i++) { tile_e[nt] = e; tile_rt[nt] = i; nt++; }
    o += cnt[e * CNTS];
  }
  *ntiles = nt;
}

// ---------------- grouped GEMM: 256x256 tile, BK=32, dbuf gload_lds, 2-barrier loop.
// 1024 threads = 16 waves (4x4), each wave computes 64x64 (identical per-wave code
// to the proven 128^2 version). 2x arithmetic intensity per staged byte vs 128^2:
// A-panel re-reads x12 (not x24), B-panel x~4 (not x8) -> L2 traffic halved.
template<int KDIM, int NDIM, int SPLITK, int EPI>
__global__ __launch_bounds__(1024, 4)
void moe_gemm(const short* __restrict__ A, const short* __restrict__ Bw,
              const int* __restrict__ tok, const float* __restrict__ wgt,
              const int* __restrict__ cnt, const int* __restrict__ offs,
              const int* __restrict__ tile_e, const int* __restrict__ tile_rt,
              const int* __restrict__ ntiles,
              short* __restrict__ hout, float* __restrict__ fout) {
  const int COLT = NDIM / 256;
  const int KS = KDIM / SPLITK;
  const int NKT = KS / 32;
  static_assert(NKT >= 2, "need at least 2 k-steps");

  int nwg = gridDim.x;
  int cpx = nwg >> 3;
  int logical = (blockIdx.x & 7) * cpx + (blockIdx.x >> 3);   // bijective XCD swizzle
  int ct = logical % COLT;
  int tile = (logical / COLT) % MAXT2;
  int sk = logical / (COLT * MAXT2);
  if (tile >= *ntiles) return;
  int e = tile_e[tile], rt = tile_rt[tile];
  int ne = cnt[e * CNTS];
  int base = offs[e];

  __shared__ __align__(16) short As[2][256 * 32];
  __shared__ __align__(16) short Bs[2][256 * 32];

  int tid = threadIdx.x;          // 0..1023
  int lane = tid & 63;
  int wid = tid >> 6;             // 0..15

  // staging map: seg = tid in [0,1024), row = seg>>2 (0..255), slot p = seg&3 holds
  // logical 16B k-chunk q = p ^ ((row ^ (row>>2)) & 3); read side applies same XOR.
  const short* aptr;
  const short* bptr;
  int lofs;
  {
    int row = tid >> 2, p = tid & 3;
    int q = p ^ ((row ^ (row >> 2)) & 3);
    int r = rt * 256 + row;
    if (r >= ne) r = ne - 1;
    size_t ga = (EPI == 0) ? (size_t)tok[e * T_TOK + r] : (size_t)(base + r);
    aptr = A + ga * KDIM + sk * KS + q * 8;
    bptr = Bw + ((size_t)e * NDIM + ct * 256 + row) * KDIM + sk * KS + q * 8;
    lofs = tid * 8;
  }

  int wr = (wid >> 2) * 64, wc = (wid & 3) * 64;
  int cb = lane >> 4;

  // loop-invariant LDS read offsets (in shorts)
  int offa[4], offb[4];
#pragma unroll
  for (int m = 0; m < 4; m++) {
    int row = wr + m * 16 + (lane & 15);
    offa[m] = row * 32 + (cb ^ ((row ^ (row >> 2)) & 3)) * 8;
  }
#pragma unroll
  for (int n = 0; n < 4; n++) {
    int row = wc + n * 16 + (lane & 15);
    offb[n] = row * 32 + (cb ^ ((row ^ (row >> 2)) & 3)) * 8;
  }

  f32x4 acc[4][4];
#pragma unroll
  for (int m = 0; m < 4; m++)
#pragma unroll
    for (int n = 0; n < 4; n++) acc[m][n] = (f32x4){0.f, 0.f, 0.f, 0.f};

  // prologue: stage tile 0 into buf 0
  gload16(aptr, &As[0][lofs]);
  gload16(bptr, &Bs[0][lofs]);
  __syncthreads();

  int cur = 0;
  for (int kt = 0; kt < NKT; ++kt) {
    if (kt + 1 < NKT) {
      int k0 = (kt + 1) * 32;
      gload16(aptr + k0, &As[cur ^ 1][lofs]);
      gload16(bptr + k0, &Bs[cur ^ 1][lofs]);
    }
    bf16x8 af[4], bv[4];
#pragma unroll
    for (int m = 0; m < 4; m++)
      af[m] = *(const bf16x8*)&As[cur][offa[m]];
#pragma unroll
    for (int n = 0; n < 4; n++)
      bv[n] = *(const bf16x8*)&Bs[cur][offb[n]];
#pragma unroll
    for (int m = 0; m < 4; m++)
#pragma unroll
      for (int n = 0; n < 4; n++)
        acc[m][n] = __builtin_amdgcn_mfma_f32_16x16x32_bf16(af[m], bv[n], acc[m][n], 0, 0, 0);
    __syncthreads();   // drains this wave's prefetch + retires LDS reads before swap
    cur ^= 1;
  }

  int colbase = ct * 256 + wc;
#pragma unroll
  for (int m = 0; m < 4; m++) {
#pragma unroll
    for (int j = 0; j < 4; j++) {
      int rloc = rt * 256 + wr + m * 16 + ((lane >> 4) << 2) + j;
      if (rloc < ne) {
        if (EPI == 0) {
          size_t hrow = (size_t)(base + rloc) * NDIM;
#pragma unroll
          for (int n = 0; n < 4; n++) {
            float v = acc[m][n][j];
            float g = 0.5f * v * (1.0f + erff(v * 0.70710678118f));
            hout[hrow + colbase + n * 16 + (lane & 15)] = f2bf(g);
          }
        } else {
          int t = tok[e * T_TOK + rloc];
          float w = wgt[e * T_TOK + rloc];
          float* orow = fout + (size_t)t * NDIM + colbase + (lane & 15);
#pragma unroll
          for (int n = 0; n < 4; n++)
            atomicAdd(orow + n * 16, w * acc[m][n][j]);
        }
      }
    }
  }
}

extern "C" void kernel_launch(void* const* d_in, const int* in_sizes, int n_in,
                              void* d_out, int out_size, void* d_ws, size_t ws_size,
                              hipStream_t stream) {
  const float* x   = (const float*)d_in[0];
  const float* gw  = (const float*)d_in[1];
  const float* wfc = (const float*)d_in[2];
  const float* wpj = (const float*)d_in[3];
  float* out = (float*)d_out;

  char* ws = (char*)d_ws;
  const size_t SZ_XB = (size_t)T_TOK * D_EMB * 2;
  const size_t SZ_W  = (size_t)N_EXP * D_EMB * DFF * 2;
  const size_t SZ_H  = (size_t)2 * T_TOK * DFF * 2;
  short* xb   = (short*)(ws);
  short* wfcT = (short*)(ws + SZ_XB);
  short* wpjT = (short*)(ws + SZ_XB + SZ_W);
  short* h    = (short*)(ws + SZ_XB + 2 * SZ_W);
  char* p2    = ws + SZ_XB + 2 * SZ_W + SZ_H;
  int*   tok  = (int*)(p2);
  float* wgt  = (float*)(p2 + (size_t)N_EXP * T_TOK * 4);
  char* p3    = p2 + (size_t)N_EXP * T_TOK * 8;
  int*   cnt     = (int*)(p3);                     // padded: N_EXP*CNTS ints
  int*   offs    = (int*)(p3 + 1024);
  int*   tile_e  = (int*)(p3 + 1024 + 64);
  int*   tile_rt = (int*)(p3 + 1024 + 64 + 512);
  int*   ntiles  = (int*)(p3 + 1024 + 64 + 1024);

  int n4 = out_size / 4;
  zero_init_kernel<<<2048, 256, 0, stream>>>((float4*)out, n4, cnt);
  cast_x_kernel<<<(T_TOK * D_EMB / 4 + 255) / 256, 256, 0, stream>>>(
      (const float4*)x, (short4*)xb, T_TOK * D_EMB / 4);
  transpose_cast_kernel<<<dim3(DFF / 64, D_EMB / 64, N_EXP), 256, 0, stream>>>(wfc, wfcT, D_EMB, DFF);
  transpose_cast_kernel<<<dim3(D_EMB / 64, DFF / 64, N_EXP), 256, 0, stream>>>(wpj, wpjT, DFF, D_EMB);
  gate_kernel<<<T_TOK / 16, 256, 0, stream>>>(x, gw, cnt, tok, wgt);
  plan_kernel<<<1, 1, 0, stream>>>(cnt, offs, tile_e, tile_rt, ntiles);
  // FC: K=768 (NKT=24), N=3072, tile 256x256. grid = 40*12 = 480 (%8==0)
  moe_gemm<D_EMB, DFF, 1, 0><<<MAXT2 * (DFF / 256), 1024, 0, stream>>>(
      xb, wfcT, tok, wgt, cnt, offs, tile_e, tile_rt, ntiles, h, nullptr);
  // PROJ: K=3072 split 2 (NKT=48), N=768. grid = 2*40*3 = 240 (%8==0)
  moe_gemm<DFF, D_EMB, 2, 1><<<2 * MAXT2 * (D_EMB / 256), 1024, 0, stream>>>(
      h, wpjT, tok, wgt, cnt, offs, tile_e, tile_rt, ntiles, nullptr, out);
}

// Round 11
// 238.167 us; speedup vs baseline: 1.4694x; 1.0275x over previous
//
#include <hip/hip_runtime.h>
#include <hip/hip_bf16.h>
#include <math.h>

#define T_TOK 4096
#define D_EMB 768
#define DFF   3072
#define N_EXP 8
#define MAXT2 40   // max 256-row tiles
#define CNTS  16   // cnt padding stride (ints)

typedef __attribute__((ext_vector_type(8))) short bf16x8;
typedef __attribute__((ext_vector_type(4))) float f32x4;

typedef __attribute__((address_space(3))) unsigned int lds_u32_t;
typedef __attribute__((address_space(1))) unsigned int glob_u32_t;

__device__ __forceinline__ void gload16(const void* g, void* l) {
  __builtin_amdgcn_global_load_lds((const glob_u32_t*)g, (lds_u32_t*)l, 16, 0, 0);
}

__device__ __forceinline__ short f2bf(float f) {
  union { __hip_bfloat16 b; short s; } u;
  u.b = __float2bfloat16(f);
  return u.s;
}

// ---------------- zero out + counters ----------------
__global__ void zero_init_kernel(float4* __restrict__ out4, int n4, int* __restrict__ cnt) {
  int i = blockIdx.x * blockDim.x + threadIdx.x;
  if (i < N_EXP * CNTS) cnt[i] = 0;
  float4 z; z.x = z.y = z.z = z.w = 0.f;
  for (int j = i; j < n4; j += gridDim.x * blockDim.x) out4[j] = z;
}

// ---------------- x fp32 -> bf16 ----------------
__global__ void cast_x_kernel(const float4* __restrict__ in, short4* __restrict__ outp, int n4) {
  int i = blockIdx.x * blockDim.x + threadIdx.x;
  if (i >= n4) return;
  float4 v = in[i];
  short4 o;
  o.x = f2bf(v.x); o.y = f2bf(v.y); o.z = f2bf(v.z); o.w = f2bf(v.w);
  outp[i] = o;
}

// ---------------- weight transpose+cast: [e][R][C] f32 -> [e][C][R] bf16 ----------------
__global__ void transpose_cast_kernel(const float* __restrict__ in, short* __restrict__ outp,
                                      int R, int C) {
  __shared__ float tile[64][65];
  int e = blockIdx.z;
  int c0 = blockIdx.x * 64, r0 = blockIdx.y * 64;
  const float* src = in + (size_t)e * R * C;
  short* dst = outp + (size_t)e * R * C;
  int tid = threadIdx.x;
#pragma unroll
  for (int it = 0; it < 4; ++it) {
    int idx = tid + it * 256;
    int r = idx >> 4;
    int c4 = idx & 15;
    float4 v = *(const float4*)&src[(size_t)(r0 + r) * C + c0 + c4 * 4];
    tile[r][c4 * 4 + 0] = v.x; tile[r][c4 * 4 + 1] = v.y;
    tile[r][c4 * 4 + 2] = v.z; tile[r][c4 * 4 + 3] = v.w;
  }
  __syncthreads();
#pragma unroll
  for (int it = 0; it < 4; ++it) {
    int idx = tid + it * 256;
    int c = idx >> 4;
    int rr = idx & 15;
    short4 o;
    o.x = f2bf(tile[rr * 4 + 0][c]);
    o.y = f2bf(tile[rr * 4 + 1][c]);
    o.z = f2bf(tile[rr * 4 + 2][c]);
    o.w = f2bf(tile[rr * 4 + 3][c]);
    *(short4*)&dst[(size_t)(c0 + c) * R + r0 + rr * 4] = o;
  }
}

// ---------------- gate: 16 tokens/block, LDS-aggregated routing ----------------
__global__ __launch_bounds__(256)
void gate_kernel(const float* __restrict__ x, const float* __restrict__ gw,
                 int* __restrict__ cnt, int* __restrict__ tok,
                 float* __restrict__ wgt) {
  __shared__ int lcnt[N_EXP];
  __shared__ int gbase[N_EXP];
  __shared__ int le[32];
  __shared__ float lw[32];
  __shared__ int lpos[32];
  int tid = threadIdx.x, lane = tid & 63, wid = tid >> 6;
  if (tid < N_EXP) lcnt[tid] = 0;
  __syncthreads();

#pragma unroll
  for (int i = 0; i < 4; i++) {
    int t = blockIdx.x * 16 + wid * 4 + i;
    float s[N_EXP];
#pragma unroll
    for (int e = 0; e < N_EXP; e++) s[e] = 0.f;
#pragma unroll
    for (int dd = 0; dd < D_EMB / 64; dd++) {
      int d = dd * 64 + lane;
      float xv = x[(size_t)t * D_EMB + d];
#pragma unroll
      for (int e = 0; e < N_EXP; e++) s[e] += xv * gw[d * N_EXP + e];
    }
#pragma unroll
    for (int e = 0; e < N_EXP; e++) {
#pragma unroll
      for (int off = 32; off > 0; off >>= 1) s[e] += __shfl_xor(s[e], off, 64);
    }
    if (lane == 0) {
      int e0 = 0;
#pragma unroll
      for (int e = 1; e < N_EXP; e++) if (s[e] > s[e0]) e0 = e;
      int e1 = -1;
#pragma unroll
      for (int e = 0; e < N_EXP; e++) {
        if (e == e0) continue;
        if (e1 < 0 || s[e] > s[e1]) e1 = e;
      }
      float p1 = __expf(s[e1] - s[e0]);
      float inv = 1.f / (1.f + p1);
      int idx = (wid * 4 + i) * 2;
      le[idx] = e0; lw[idx] = inv;           lpos[idx] = atomicAdd(&lcnt[e0], 1);
      le[idx + 1] = e1; lw[idx + 1] = p1 * inv; lpos[idx + 1] = atomicAdd(&lcnt[e1], 1);
    }
  }
  __syncthreads();
  if (tid < N_EXP) gbase[tid] = atomicAdd(&cnt[tid * CNTS], lcnt[tid]);
  __syncthreads();
  if (tid < 32) {
    int e = le[tid];
    int t = blockIdx.x * 16 + (tid >> 1);
    int p = gbase[e] + lpos[tid];
    tok[e * T_TOK + p] = t;
    wgt[e * T_TOK + p] = lw[tid];
  }
}

// ---------------- plan: offsets + compacted (expert, 256-row-tile) list ----------------
__global__ void plan_kernel(const int* __restrict__ cnt, int* __restrict__ offs,
                            int* __restrict__ tile_e, int* __restrict__ tile_rt,
                            int* __restrict__ ntiles) {
  if (threadIdx.x != 0 || blockIdx.x != 0) return;
  int o = 0, nt = 0;
  for (int e = 0; e < N_EXP; e++) {
    offs[e] = o;
    int tc = (cnt[e * CNTS] + 255) >> 8;
    for (int i = 0; i < tc; i++) { tile_e[nt] = e; tile_rt[nt] = i; nt++; }
    o += cnt[e * CNTS];
  }
  *ntiles = nt;
}

// ---------------- grouped GEMM: 256x128 tile, BK=64, 8 waves, 3-slot LDS rotation,
// 8-phase-style schedule with COUNTED vmcnt (T3+T4) + setprio (T5).
// Tile T reads slot T%3; tile T+2 is staged into slot (T+2)%3 during T's two phases
// (that slot was last read at tile T-1 -> free). vmcnt(6) at each tile's closing
// barrier guarantees tile T+1 (older than the 6 in-flight T+2 loads) has landed.
// Never vmcnt(0) in steady state. Raw s_barrier only (no __syncthreads drain).
template<int KDIM, int NDIM, int SPLITK, int EPI>
__global__ __launch_bounds__(512, 2)
void moe_gemm(const short* __restrict__ A, const short* __restrict__ Bw,
              const int* __restrict__ tok, const float* __restrict__ wgt,
              const int* __restrict__ cnt, const int* __restrict__ offs,
              const int* __restrict__ tile_e, const int* __restrict__ tile_rt,
              const int* __restrict__ ntiles,
              short* __restrict__ hout, float* __restrict__ fout) {
  const int COLT = NDIM / 128;
  const int KS = KDIM / SPLITK;
  const int NT = KS / 64;               // K-tiles: FC 12, PROJ 24
  static_assert(NT % 3 == 0 && NT >= 6, "3-slot rotation needs NT%3==0");

  int nwg = gridDim.x;
  int cpx = nwg >> 3;
  int logical = (blockIdx.x & 7) * cpx + (blockIdx.x >> 3);   // bijective XCD swizzle
  int ct = logical % COLT;
  int tile = (logical / COLT) % MAXT2;
  int sk = logical / (COLT * MAXT2);
  if (tile >= *ntiles) return;
  int e = tile_e[tile], rt = tile_rt[tile];
  int ne = cnt[e * CNTS];
  int base = offs[e];

  // slot = A[256][64] (16384 shorts) + B[128][64] (8192 shorts) = 24576 shorts
  __shared__ __align__(16) short LDS[3 * 24576];   // 144 KiB
  const int SL0 = 0, SL1 = 24576, SL2 = 49152;

  int tid = threadIdx.x;        // 0..511
  int lane = tid & 63;
  int wid = tid >> 6;           // 0..7 -> waves 4M x 2N

  // ---- staging pointers: 3072 segs/K-tile, 2 stage-phases x 3 loads/thread.
  // seg<2048: A row=seg>>3; else B row=(seg-2048)>>3. chunk p=seg&7 holds logical
  // q = p ^ (row&7) (same XOR on read side).
  const short* gp00; const short* gp01; const short* gp02;
  const short* gp10; const short* gp11; const short* gp12;
  int lo00, lo01, lo02, lo10, lo11, lo12;
#define MKSEG(SEG, GP, LO) do {                                              \
    int s_ = (SEG);                                                          \
    if (s_ < 2048) {                                                         \
      int row_ = s_ >> 3, p_ = s_ & 7;                                       \
      int q_ = p_ ^ (row_ & 7);                                              \
      int r_ = rt * 256 + row_; if (r_ >= ne) r_ = ne - 1;                   \
      size_t ga_ = (EPI == 0) ? (size_t)tok[e * T_TOK + r_] : (size_t)(base + r_); \
      GP = A + ga_ * KDIM + sk * KS + q_ * 8;                                \
      LO = s_ * 8;                                                           \
    } else {                                                                 \
      int t_ = s_ - 2048;                                                    \
      int row_ = t_ >> 3, p_ = t_ & 7;                                       \
      int q_ = p_ ^ (row_ & 7);                                              \
      GP = Bw + ((size_t)e * NDIM + ct * 128 + row_) * KDIM + sk * KS + q_ * 8; \
      LO = 16384 + t_ * 8;                                                   \
    }                                                                        \
  } while (0)
  MKSEG(tid,        gp00, lo00);
  MKSEG(tid + 512,  gp01, lo01);
  MKSEG(tid + 1024, gp02, lo02);
  MKSEG(tid + 1536, gp10, lo10);
  MKSEG(tid + 2048, gp11, lo11);
  MKSEG(tid + 2560, gp12, lo12);
#undef MKSEG

  int wr = (wid >> 1) * 64;     // 0,64,128,192
  int wc = (wid & 1) * 64;      // 0,64
  int cb = lane >> 4;           // 0..3

  // read offsets (shorts) per k-half
  int offA0[4], offA1[4], offB0[4], offB1[4];
#pragma unroll
  for (int m = 0; m < 4; m++) {
    int row = wr + m * 16 + (lane & 15);
    offA0[m] = row * 64 + ((cb ^ (row & 7)) * 8);
    offA1[m] = row * 64 + (((cb + 4) ^ (row & 7)) * 8);
  }
#pragma unroll
  for (int n = 0; n < 4; n++) {
    int row = wc + n * 16 + (lane & 15);
    offB0[n] = row * 64 + ((cb ^ (row & 7)) * 8);
    offB1[n] = row * 64 + (((cb + 4) ^ (row & 7)) * 8);
  }

  f32x4 acc[4][4];
#pragma unroll
  for (int m = 0; m < 4; m++)
#pragma unroll
    for (int n = 0; n < 4; n++) acc[m][n] = (f32x4){0.f, 0.f, 0.f, 0.f};

#define STAGE0(SST, KOFF) do {                       \
    gload16(gp00 + (KOFF), &LDS[(SST) + lo00]);      \
    gload16(gp01 + (KOFF), &LDS[(SST) + lo01]);      \
    gload16(gp02 + (KOFF), &LDS[(SST) + lo02]); } while (0)
#define STAGE1(SST, KOFF) do {                       \
    gload16(gp10 + (KOFF), &LDS[(SST) + lo10]);      \
    gload16(gp11 + (KOFF), &LDS[(SST) + lo11]);      \
    gload16(gp12 + (KOFF), &LDS[(SST) + lo12]); } while (0)

// phase: dsr 8 x b128 -> stage 3 -> [vmcnt] -> barrier -> setprio+16 MFMA -> barrier
#define PH(SRD, OA, OB, SST, DOST, WHICH, KOFF, VM) do {                     \
    bf16x8 af_[4], bv_[4];                                                   \
    _Pragma("unroll") for (int m_ = 0; m_ < 4; ++m_)                         \
      af_[m_] = *(const bf16x8*)&LDS[(SRD) + OA[m_]];                        \
    _Pragma("unroll") for (int n_ = 0; n_ < 4; ++n_)                         \
      bv_[n_] = *(const bf16x8*)&LDS[(SRD) + OB[n_]];                        \
    if (DOST) { if ((WHICH) == 0) STAGE0((SST), (KOFF)); else STAGE1((SST), (KOFF)); } \
    if ((VM) == 6) asm volatile("s_waitcnt vmcnt(6)" ::: "memory");          \
    else if ((VM) == 0) asm volatile("s_waitcnt vmcnt(0)" ::: "memory");     \
    __builtin_amdgcn_s_barrier();                                            \
    __builtin_amdgcn_s_setprio(1);                                           \
    _Pragma("unroll") for (int m_ = 0; m_ < 4; ++m_)                         \
      _Pragma("unroll") for (int n_ = 0; n_ < 4; ++n_)                       \
        acc[m_][n_] = __builtin_amdgcn_mfma_f32_16x16x32_bf16(               \
            af_[m_], bv_[n_], acc[m_][n_], 0, 0, 0);                         \
    __builtin_amdgcn_s_setprio(0);                                           \
    __builtin_amdgcn_s_barrier();                                            \
  } while (0)

// tile = 2 phases (k-half 0, k-half 1); stage phases 0/1 target tile T+2's slot
#define TILE(SRD, SST, DOST, KOFF, VMB)                                      \
    PH((SRD), offA0, offB0X, (SST), (DOST), 0, (KOFF), -1);                  \
    PH((SRD), offA1, offB1X, (SST), (DOST), 1, (KOFF), (VMB))
  // B offsets are relative to slot base + 16384:
  int offB0X[4], offB1X[4];
#pragma unroll
  for (int n = 0; n < 4; n++) { offB0X[n] = 16384 + offB0[n]; offB1X[n] = 16384 + offB1[n]; }

  // prologue: stage tile0 -> slot0 (6 loads), tile1 -> slot1 (6); wait T0 landed.
  STAGE0(SL0, 0);  STAGE1(SL0, 0);
  STAGE0(SL1, 64); STAGE1(SL1, 64);
  asm volatile("s_waitcnt vmcnt(6)" ::: "memory");
  __builtin_amdgcn_s_barrier();

#pragma unroll 1
  for (int g = 0; g < NT / 3 - 1; ++g) {
    int k2 = (3 * g + 2) * 64, k3 = (3 * g + 3) * 64, k4 = (3 * g + 4) * 64;
    TILE(SL0, SL2, 1, k2, 6);
    TILE(SL1, SL0, 1, k3, 6);
    TILE(SL2, SL1, 1, k4, 6);
  }
  // peeled last group: T = NT-3, NT-2, NT-1
  TILE(SL0, SL2, 1, (NT - 1) * 64, 6);
  TILE(SL1, SL0, 0, 0, 0);
  TILE(SL2, SL1, 0, 0, -1);

#undef TILE
#undef PH
#undef STAGE0
#undef STAGE1

  // epilogue: acc[m][n][j] -> row = rt*256 + wr + m*16 + (lane>>4)*4 + j,
  //                           col = ct*128 + wc + n*16 + (lane&15)
  int colbase = ct * 128 + wc;
#pragma unroll
  for (int m = 0; m < 4; m++) {
#pragma unroll
    for (int j = 0; j < 4; j++) {
      int rloc = rt * 256 + wr + m * 16 + ((lane >> 4) << 2) + j;
      if (rloc < ne) {
        if (EPI == 0) {
          size_t hrow = (size_t)(base + rloc) * NDIM;
#pragma unroll
          for (int n = 0; n < 4; n++) {
            float v = acc[m][n][j];
            float g = 0.5f * v * (1.0f + erff(v * 0.70710678118f));
            hout[hrow + colbase + n * 16 + (lane & 15)] = f2bf(g);
          }
        } else {
          int t = tok[e * T_TOK + rloc];
          float w = wgt[e * T_TOK + rloc];
          float* orow = fout + (size_t)t * NDIM + colbase + (lane & 15);
#pragma unroll
          for (int n = 0; n < 4; n++)
            atomicAdd(orow + n * 16, w * acc[m][n][j]);
        }
      }
    }
  }
}

extern "C" void kernel_launch(void* const* d_in, const int* in_sizes, int n_in,
                              void* d_out, int out_size, void* d_ws, size_t ws_size,
                              hipStream_t stream) {
  const float* x   = (const float*)d_in[0];
  const float* gw  = (const float*)d_in[1];
  const float* wfc = (const float*)d_in[2];
  const float* wpj = (const float*)d_in[3];
  float* out = (float*)d_out;

  char* ws = (char*)d_ws;
  const size_t SZ_XB = (size_t)T_TOK * D_EMB * 2;
  const size_t SZ_W  = (size_t)N_EXP * D_EMB * DFF * 2;
  const size_t SZ_H  = (size_t)2 * T_TOK * DFF * 2;
  short* xb   = (short*)(ws);
  short* wfcT = (short*)(ws + SZ_XB);
  short* wpjT = (short*)(ws + SZ_XB + SZ_W);
  short* h    = (short*)(ws + SZ_XB + 2 * SZ_W);
  char* p2    = ws + SZ_XB + 2 * SZ_W + SZ_H;
  int*   tok  = (int*)(p2);
  float* wgt  = (float*)(p2 + (size_t)N_EXP * T_TOK * 4);
  char* p3    = p2 + (size_t)N_EXP * T_TOK * 8;
  int*   cnt     = (int*)(p3);                     // padded: N_EXP*CNTS ints
  int*   offs    = (int*)(p3 + 1024);
  int*   tile_e  = (int*)(p3 + 1024 + 64);
  int*   tile_rt = (int*)(p3 + 1024 + 64 + 512);
  int*   ntiles  = (int*)(p3 + 1024 + 64 + 1024);

  int n4 = out_size / 4;
  zero_init_kernel<<<2048, 256, 0, stream>>>((float4*)out, n4, cnt);
  cast_x_kernel<<<(T_TOK * D_EMB / 4 + 255) / 256, 256, 0, stream>>>(
      (const float4*)x, (short4*)xb, T_TOK * D_EMB / 4);
  transpose_cast_kernel<<<dim3(DFF / 64, D_EMB / 64, N_EXP), 256, 0, stream>>>(wfc, wfcT, D_EMB, DFF);
  transpose_cast_kernel<<<dim3(D_EMB / 64, DFF / 64, N_EXP), 256, 0, stream>>>(wpj, wpjT, DFF, D_EMB);
  gate_kernel<<<T_TOK / 16, 256, 0, stream>>>(x, gw, cnt, tok, wgt);
  plan_kernel<<<1, 1, 0, stream>>>(cnt, offs, tile_e, tile_rt, ntiles);
  // FC: K=768 (NT=12), N=3072, tile 256x128. grid = 40*24 = 960 (%8==0)
  moe_gemm<D_EMB, DFF, 1, 0><<<MAXT2 * (DFF / 128), 512, 0, stream>>>(
      xb, wfcT, tok, wgt, cnt, offs, tile_e, tile_rt, ntiles, h, nullptr);
  // PROJ: K=3072 split 2 (NT=24), N=768. grid = 2*40*6 = 480 (%8==0)
  moe_gemm<DFF, D_EMB, 2, 1><<<2 * MAXT2 * (D_EMB / 128), 512, 0, stream>>>(
      h, wpjT, tok, wgt, cnt, offs, tile_e, tile_rt, ntiles, nullptr, out);
}